// Round 6
// baseline (231.717 us; speedup 1.0000x reference)
//
#include <hip/hip_runtime.h>
#include <stdint.h>

// ---------------------------------------------------------------------------
// SelfAttn: B=4, W=H=64, C=256, C2=128, N=W*H=4096.
// pq = raw q buffer viewed [128,4096]  (Q_rows[n,c] = q_flat[c*4096+n])
// pv = raw v buffer viewed [256,4096]  (natural layout == PV B-operand layout)
// energy = Qrm @ Krm^T (K=128), softmax over keys (fixed ref m=0),
// O[n,c] = sum_m P[n,m] V[m,c];  final[b,c*4096+n] = gamma*O/l + x.
//
// R5 post-mortem: attn cycle budget was LDS-dominated; Vs tile had ZERO
// cross-wave reuse (each wave read back only what it staged). R6: V goes
// global->register B-operands directly (prefetched 1 tile ahead); Ps
// double-buffered -> 1 barrier/kt. LDS instrs/wave/kt: 28 -> 12.
// ---------------------------------------------------------------------------

typedef __attribute__((ext_vector_type(8)))  short short8;   // 8 x bf16
typedef __attribute__((ext_vector_type(4)))  float f32x4;
typedef __attribute__((ext_vector_type(16))) float f32x16;
typedef __attribute__((ext_vector_type(4)))  unsigned short u16x4;

#define MFMA16 __builtin_amdgcn_mfma_f32_16x16x32_bf16
#define MFMA32 __builtin_amdgcn_mfma_f32_32x32x16_bf16

__device__ __forceinline__ unsigned short f2bf(float f) {
    union { float f; uint32_t u; } v; v.f = f;
    uint32_t r = (v.u + 0x7FFFu + ((v.u >> 16) & 1u)) >> 16;   // RNE
    return (unsigned short)r;
}
__device__ __forceinline__ float bf2f(unsigned short h) {
    union { uint32_t u; float f; } v; v.u = ((uint32_t)h) << 16;
    return v.f;
}

// --- K1: Wt[512][256] bf16 (transposed, fused qkv) + bias[512] f32 ---------
__global__ void prep_w(const float* __restrict__ Wq, const float* __restrict__ bq,
                       const float* __restrict__ Wk, const float* __restrict__ bk,
                       const float* __restrict__ Wv, const float* __restrict__ bv,
                       unsigned short* __restrict__ Wt, float* __restrict__ bias) {
    int g = blockIdx.x * 256 + threadIdx.x;
    int c = g & 255, d = g >> 8;
    float val;
    if (d < 128)      val = Wq[c * 128 + d];
    else if (d < 256) val = Wk[c * 128 + (d - 128)];
    else              val = Wv[c * 256 + (d - 256)];
    Wt[d * 256 + c] = f2bf(val);
    if (g < 512) {
        float bb;
        if (g < 128)      bb = bq[g];
        else if (g < 256) bb = bk[g - 128];
        else              bb = bv[g - 256];
        bias[g] = bb;
    }
}

// --- K2: fused QKV projection. 512 blocks (unchanged from R5) --------------
__global__ __launch_bounds__(256) void proj(
        const float* __restrict__ x, const unsigned short* __restrict__ Wt,
        const float* __restrict__ bias,
        unsigned short* __restrict__ Qrm, unsigned short* __restrict__ Krm,
        unsigned short* __restrict__ Vbf) {
    __shared__ unsigned short T[128 * 136];
    int bid = blockIdx.x;
    int tid = threadIdx.x;
    int wave = tid >> 6, lane = tid & 63;
    int l16 = lane & 15, quad = lane >> 4;

    int kind, b, a, vh = 0;
    if (bid < 256) { kind = bid >> 7; int s = bid & 127; b = s >> 5; a = s & 31; }
    else           { kind = 2; int s = bid - 256; vh = s >> 7; b = (s >> 5) & 3; a = s & 31; }

    short8 af[2][8];
    #pragma unroll
    for (int g = 0; g < 2; ++g) {
        int p_local = wave * 32 + g * 16 + l16;
        int pix = (kind == 2) ? (b * 4096 + a * 128 + p_local)
                              : (b * 4096 + a + 32 * p_local);
        const float* xr = x + (size_t)pix * 256;
        #pragma unroll
        for (int kk = 0; kk < 8; ++kk) {
            f32x4 u0 = *(const f32x4*)(xr + kk * 32 + quad * 8);
            f32x4 u1 = *(const f32x4*)(xr + kk * 32 + quad * 8 + 4);
            short8 h;
            h[0] = (short)f2bf(u0[0]); h[1] = (short)f2bf(u0[1]);
            h[2] = (short)f2bf(u0[2]); h[3] = (short)f2bf(u0[3]);
            h[4] = (short)f2bf(u1[0]); h[5] = (short)f2bf(u1[1]);
            h[6] = (short)f2bf(u1[2]); h[7] = (short)f2bf(u1[3]);
            af[g][kk] = h;
        }
    }

    if (kind < 2) {
        int dbase = kind * 128;
        unsigned short* out = kind ? Krm : Qrm;
        #pragma unroll 1
        for (int dt = 0; dt < 8; ++dt) {
            int d = dbase + dt * 16 + l16;
            float bval = bias[d];
            f32x4 acc0 = {0.f,0.f,0.f,0.f}, acc1 = {0.f,0.f,0.f,0.f};
            #pragma unroll
            for (int kk = 0; kk < 8; ++kk) {
                short8 wrow = *(const short8*)(Wt + d * 256 + kk * 32 + quad * 8);
                acc0 = MFMA16(af[0][kk], wrow, acc0, 0, 0, 0);
                acc1 = MFMA16(af[1][kk], wrow, acc1, 0, 0, 0);
            }
            #pragma unroll
            for (int g = 0; g < 2; ++g) {
                f32x4 acc = g ? acc1 : acc0;
                u16x4 pk;
                #pragma unroll
                for (int reg = 0; reg < 4; ++reg) pk[reg] = f2bf(acc[reg] + bval);
                *(u16x4*)(T + (dt * 16 + l16) * 136 + wave * 32 + g * 16 + quad * 4) = pk;
            }
        }
        __syncthreads();
        unsigned short* ob = out + (b << 19) + a * 128 * 128;
        #pragma unroll
        for (int it = 0; it < 8; ++it) {
            int ci = it * 256 + tid;
            int row = ci >> 4, cj = ci & 15;
            *(short8*)(ob + row * 128 + cj * 8) = *(const short8*)(T + row * 136 + cj * 8);
        }
    } else {
        #pragma unroll 1
        for (int dt = 0; dt < 8; ++dt) {
            int d = 256 + vh * 128 + dt * 16 + l16;
            f32x4 acc0 = {0.f,0.f,0.f,0.f}, acc1 = {0.f,0.f,0.f,0.f};
            #pragma unroll
            for (int kk = 0; kk < 8; ++kk) {
                short8 wrow = *(const short8*)(Wt + d * 256 + kk * 32 + quad * 8);
                acc0 = MFMA16(wrow, af[0][kk], acc0, 0, 0, 0);   // A=W, B=x -> D^T
                acc1 = MFMA16(wrow, af[1][kk], acc1, 0, 0, 0);
            }
            int dvl = dt * 16 + quad * 4;
            f32x4 bv4 = *(const f32x4*)(bias + 256 + vh * 128 + dvl);
            #pragma unroll
            for (int g = 0; g < 2; ++g) {
                f32x4 acc = g ? acc1 : acc0;
                u16x4 pk;
                #pragma unroll
                for (int reg = 0; reg < 4; ++reg) pk[reg] = f2bf(acc[reg] + bv4[reg]);
                int p_local = wave * 32 + g * 16 + l16;
                *(u16x4*)(T + p_local * 136 + dvl) = pk;
            }
        }
        __syncthreads();
        #pragma unroll
        for (int it = 0; it < 8; ++it) {
            int cid = it * 256 + tid;
            int c_local = cid >> 8, w = cid & 255;
            int p_local = c_local * 16 + (w >> 4);
            int m = (w >> 4) * 256 + vh * 128 + (w & 15) * 8;
            *(short8*)(Vbf + (b << 20) + (size_t)(a * 8 + c_local) * 4096 + m)
                = *(const short8*)(T + p_local * 136 + (w & 15) * 8);
        }
    }
}

// --- K3: flash attention. grid 512 = 64 qtiles x (4 b x 2 ks) --------------
// 64 queries/block, 64-key tiles (32 tiles), 32x32x16 MFMA.
// QK: wave (mt,nt): S^T[mt][nt] with K prefetched in registers.
// V: NO LDS staging (no cross-wave reuse) -> per-wave register B-operands,
// prefetched one tile ahead. Ps double-buffered -> 1 barrier per tile.
__global__ __launch_bounds__(256, 2) void attn(
        const unsigned short* __restrict__ Qrm, const unsigned short* __restrict__ Krm,
        const unsigned short* __restrict__ Vbf, unsigned short* __restrict__ Opart,
        float* __restrict__ Lpart) {
    __shared__ unsigned short Ps[2 * 64 * 72];         // P [q=64][m=64 +pad], x2 buf

    int bid = blockIdx.x;
    int comb = bid & 7, qt = bid >> 3;                 // same (b,ks) -> same XCD
    int b = comb >> 1, ks = comb & 1;
    int tid = threadIdx.x, wave = tid >> 6, lane = tid & 63;
    int l32 = lane & 31, half = lane >> 5;
    int mt = wave & 1, nt = wave >> 1;

    const unsigned short* Qb = Qrm + (b << 19);
    const unsigned short* Kb = Krm + (b << 19);
    const unsigned short* Vb = Vbf + (b << 20);

    int q0 = qt * 64;

    short8 qf[8];                                      // B=Q for wave's 32 queries
    {
        const unsigned short* qrow = Qb + (q0 + nt * 32 + l32) * 128 + half * 8;
        #pragma unroll
        for (int kk = 0; kk < 8; ++kk) qf[kk] = *(const short8*)(qrow + kk * 16);
    }

    f32x16 O[2][2];                                    // [qtile][ctile]
    #pragma unroll
    for (int i = 0; i < 2; ++i)
        #pragma unroll
        for (int j = 0; j < 2; ++j)
            #pragma unroll
            for (int r = 0; r < 16; ++r) O[i][j][r] = 0.f;
    float l_run = 0.f;

    const int m_base = ks * 2048;

    // tile-0 prefetch: K A-frags + V B-frags (wave's 2 ctiles x 4 k-chunks)
    short8 kf[8];
    {
        const unsigned short* krow = Kb + (m_base + mt * 32 + l32) * 128 + half * 8;
        #pragma unroll
        for (int kk = 0; kk < 8; ++kk) kf[kk] = *(const short8*)(krow + kk * 16);
    }
    short8 vreg[2][4];
    #pragma unroll
    for (int c2 = 0; c2 < 2; ++c2)
        #pragma unroll
        for (int k2 = 0; k2 < 4; ++k2)
            vreg[c2][k2] = *(const short8*)(Vb + (size_t)((wave * 2 + c2) * 32 + l32) * 4096
                                            + m_base + k2 * 16 + half * 8);

    #pragma unroll 1
    for (int kt = 0; kt < 32; ++kt) {
        int m0 = m_base + kt * 64;
        unsigned short* Pb = Ps + (kt & 1) * (64 * 72);

        // S^T[m][n]: A=kf (keys), B=qf (queries); col n = l32,
        // row m (within mtile) = (r&3)+8*(r>>2)+4*half.
        f32x16 S;
        #pragma unroll
        for (int r = 0; r < 16; ++r) S[r] = 0.f;
        #pragma unroll
        for (int kk = 0; kk < 8; ++kk) S = MFMA32(kf[kk], qf[kk], S, 0, 0, 0);

        // fixed-ref softmax (m=0): p = exp(S); l += sum p; pack -> Ps
        float rs = 0.f;
        #pragma unroll
        for (int g = 0; g < 4; ++g) {
            u16x4 pk;
            #pragma unroll
            for (int i = 0; i < 4; ++i) {
                float p = __expf(S[g * 4 + i]);
                rs += p;
                pk[i] = f2bf(p);
            }
            // P[q][m]: q = nt*32+l32, m = mt*32 + g*8 + half*4 + i
            *(u16x4*)(Pb + (nt * 32 + l32) * 72 + mt * 32 + g * 8 + half * 4) = pk;
        }
        rs += __shfl_xor(rs, 32);
        l_run += rs;

        __syncthreads();                               // Ps[buf] ready

        if (kt < 31) {                                 // K prefetch (post-drain)
            const unsigned short* krow = Kb + (m0 + 64 + mt * 32 + l32) * 128 + half * 8;
            #pragma unroll
            for (int kk = 0; kk < 8; ++kk) kf[kk] = *(const short8*)(krow + kk * 16);
        }

        // PV: A = P rows (q), B = vreg (wave ctiles {2w,2w+1})
        #pragma unroll
        for (int k2 = 0; k2 < 4; ++k2) {
            short8 pa0 = *(const short8*)(Pb + (l32) * 72 + k2 * 16 + half * 8);
            short8 pa1 = *(const short8*)(Pb + (32 + l32) * 72 + k2 * 16 + half * 8);
            O[0][0] = MFMA32(pa0, vreg[0][k2], O[0][0], 0, 0, 0);
            O[0][1] = MFMA32(pa0, vreg[1][k2], O[0][1], 0, 0, 0);
            O[1][0] = MFMA32(pa1, vreg[0][k2], O[1][0], 0, 0, 0);
            O[1][1] = MFMA32(pa1, vreg[1][k2], O[1][1], 0, 0, 0);
        }

        if (kt < 31) {                                 // V prefetch for kt+1
            int m1 = m0 + 64;
            #pragma unroll
            for (int c2 = 0; c2 < 2; ++c2)
                #pragma unroll
                for (int k2 = 0; k2 < 4; ++k2)
                    vreg[c2][k2] = *(const short8*)(Vb + (size_t)((wave * 2 + c2) * 32 + l32) * 4096
                                                    + m1 + k2 * 16 + half * 8);
        }
    }

    // epilogue: unnormalized O + per-query l partials
    unsigned short* Op = Opart + ((size_t)(ks * 4 + b) << 20);
    #pragma unroll
    for (int q2 = 0; q2 < 2; ++q2)
        #pragma unroll
        for (int c2 = 0; c2 < 2; ++c2) {
            int c = (wave * 2 + c2) * 32 + l32;
            #pragma unroll
            for (int r = 0; r < 16; ++r) {
                int n = q0 + q2 * 32 + (r & 3) + 8 * (r >> 2) + 4 * half;
                Op[(size_t)n * 256 + c] = f2bf(O[q2][c2][r]);
            }
        }
    if (half == 0) {
        int n = q0 + nt * 32 + l32;
        Lpart[((ks * 2 + mt) * 4 + b) * 4096 + n] = l_run;
    }
}

// --- K4: merge 2 key-splits (4 l-partials), gamma*O/l + x, transpose -------
__global__ __launch_bounds__(256) void merge_out(
        const unsigned short* __restrict__ Opart, const float* __restrict__ Lpart,
        const float* __restrict__ x, const float* __restrict__ gamma,
        float* __restrict__ out) {
    __shared__ float tile[64][65];
    __shared__ float wsm[64];
    int b  = blockIdx.x >> 6;
    int n0 = (blockIdx.x & 63) << 6;
    int tid = threadIdx.x;
    float g = gamma[0];
    if (tid < 64) {
        int n = n0 + tid;
        float L = 0.f;
        #pragma unroll
        for (int s = 0; s < 4; ++s) L += Lpart[(s * 4 + b) * 4096 + n];
        wsm[tid] = g / L;
    }
    __syncthreads();
    int cl  = tid & 63, nl4 = tid >> 6;
    int nl  = tid & 63, cl4 = tid >> 6;
    for (int cc = 0; cc < 4; ++cc) {
        for (int i = 0; i < 16; ++i) {
            int n = n0 + i * 4 + nl4;
            int c = (cc << 6) + cl;
            float On = 0.f;
            #pragma unroll
            for (int s = 0; s < 2; ++s)
                On += bf2f(Opart[((size_t)(s * 4 + b) << 20) + (size_t)n * 256 + c]);
            tile[cl][i * 4 + nl4] = On * wsm[i * 4 + nl4];
        }
        __syncthreads();
        for (int j = 0; j < 16; ++j) {
            int c = (cc << 6) + j * 4 + cl4;
            int idx = (b << 20) + c * 4096 + n0 + nl;
            out[idx] = tile[j * 4 + cl4][nl] + x[idx];
        }
        __syncthreads();
    }
}

// ---------------------------------------------------------------------------
extern "C" void kernel_launch(void* const* d_in, const int* in_sizes, int n_in,
                              void* d_out, int out_size, void* d_ws, size_t ws_size,
                              hipStream_t stream) {
    const float* x     = (const float*)d_in[0];
    const float* Wq    = (const float*)d_in[1];
    const float* bq    = (const float*)d_in[2];
    const float* Wk    = (const float*)d_in[3];
    const float* bk    = (const float*)d_in[4];
    const float* Wv    = (const float*)d_in[5];
    const float* bv    = (const float*)d_in[6];
    const float* gamma = (const float*)d_in[7];
    float* out = (float*)d_out;

    if (ws_size < 34080768u) return;   // need ~33 MB scratch

    char* ws = (char*)d_ws;
    unsigned short* Wt    = (unsigned short*)(ws);             //    262,144 B
    float*          bias  = (float*)        (ws +   262144);   //      2,048 B
    unsigned short* Qrm   = (unsigned short*)(ws +   264192);  //  4,194,304 B
    unsigned short* Krm   = (unsigned short*)(ws +  4458496);  //  4,194,304 B
    unsigned short* Vbf   = (unsigned short*)(ws +  8652800);  //  8,388,608 B
    unsigned short* Opart = (unsigned short*)(ws + 17041408);  // 16,777,216 B
    float*          Lpart = (float*)        (ws + 33818624);   //    262,144 B

    prep_w   <<<512, 256, 0, stream>>>(Wq, bq, Wk, bk, Wv, bv, Wt, bias);
    proj     <<<512, 256, 0, stream>>>(x, Wt, bias, Qrm, Krm, Vbf);
    attn     <<<512, 256, 0, stream>>>(Qrm, Krm, Vbf, Opart, Lpart);
    merge_out<<<256, 256, 0, stream>>>(Opart, Lpart, x, gamma, out);
}